// Round 3
// baseline (402.474 us; speedup 1.0000x reference)
//
#include <hip/hip_runtime.h>
#include <stdint.h>

// QuantConv1d: out[m][n] = (sum_k x[m][k]*w[k][n]) * scale[n] + bias[n]
// m=256, k=4096, n=16384. w arrives as int32 (harness-widened int8): 256 MiB stream.
// R2 was latency-bound: 1 block/CU + 2 barriers/iter = serial stop-and-go (~155us).
// R3: BN=32 -> 512 blocks = 2 blocks/CU (cross-block overlap of barrier stalls),
// double-buffered LDS -> 1 barrier/iter, wave-tile 32x32 (1 acc, low VGPR).

typedef short bf16x8 __attribute__((ext_vector_type(8)));   // 8 bf16 = 16 B (MFMA A/B frag)
typedef float f32x16 __attribute__((ext_vector_type(16)));  // MFMA 32x32 accumulator
typedef int   i32x4  __attribute__((ext_vector_type(4)));
typedef unsigned short u16x4 __attribute__((ext_vector_type(4)));

#define K_DIM 4096
#define N_DIM 16384
#define BK 128
#define BN 32
#define NIT (K_DIM / BK)   // 32 K-iterations
#define KSTEPS 256         // K_DIM/16 total MFMA k-steps

__device__ __forceinline__ unsigned fbits(float f) {
  union { float f; unsigned u; } c; c.f = f; return c.u;
}
__device__ __forceinline__ unsigned short bf16rne(float f) {
  unsigned u = fbits(f);
  return (unsigned short)((u + 0x7FFFu + ((u >> 16) & 1u)) >> 16);
}

// ---------------- kernel 1: x fp32 -> bf16, A-fragment-major ----------------
// chunk c = (mt*256 + ks)*64 + lane holds A[m = mt*32 + (lane&31)]
//                                        [k = ks*16 + (lane>>5)*8 .. +8]  (16 B)
// => a wave's A-frag read for (mt, ks) is 64 contiguous 16 B chunks = 1 KiB.
__global__ __launch_bounds__(256) void cvt_x_frag(const float* __restrict__ x,
                                                  unsigned short* __restrict__ xb) {
  int c    = blockIdx.x * 256 + threadIdx.x;   // 131072 chunks
  int lane = c & 63;
  int ks   = (c >> 6) & 255;
  int mt   = c >> 14;
  int row  = mt * 32 + (lane & 31);
  int k0   = ks * 16 + (lane >> 5) * 8;
  const float4* p = (const float4*)(x + row * K_DIM + k0);
  float4 v0 = p[0], v1 = p[1];
  u16x4 o0, o1;
  o0.x = bf16rne(v0.x); o0.y = bf16rne(v0.y); o0.z = bf16rne(v0.z); o0.w = bf16rne(v0.w);
  o1.x = bf16rne(v1.x); o1.y = bf16rne(v1.y); o1.z = bf16rne(v1.z); o1.w = bf16rne(v1.w);
  u16x4* dst = (u16x4*)(xb + (size_t)c * 8);
  dst[0] = o0;
  dst[1] = o1;
}

// ---------------- kernel 2: GEMM ----------------
// block: 512 thr = 8 waves; wave w computes m-tile w (32 rows) x block's 32 cols.
// grid: 512 blocks (2/CU); block bx owns cols [bx*32, bx*32+32) for ALL 256 rows
// => every W element fetched from HBM exactly once; 128B row segments = 1 line.
__global__ __launch_bounds__(512, 4) void gemm_qconv(
    const unsigned short* __restrict__ xb,   // A-fragment-major bf16 (see cvt)
    const int* __restrict__ w,               // [4096][16384] int32
    const float* __restrict__ scale,
    const float* __restrict__ bias,
    float* __restrict__ out) {
  // B fragment slots: kstep s (0..7), slot = s*64 + khalf*32 + n; reader lane l
  // reads slot==l => contiguous ds_read_b128, conflict-free. Double-buffered.
  __shared__ i32x4 Blds[2][8 * 64];          // 2 x 8 KiB

  const int tid  = threadIdx.x;
  const int lane = tid & 63;
  const int wave = tid >> 6;                 // 0..7 : m-tile
  const int l31  = lane & 31;
  const int half = lane >> 5;
  const int n0   = blockIdx.x * BN;

  // ---- W staging: thread t covers 8 consecutive k-rows of ONE n column ----
  const int kcol = tid & 31;                 // n column within stripe
  const int k8   = tid >> 5;                 // 0..15 : k-rows [k8*8, k8*8+8)
  const int sW   = k8 >> 1;                  // kstep this thread feeds
  const int hW   = k8 & 1;                   // k-half within kstep
  const int slot = sW * 64 + hW * 32 + kcol;

  const int* wbase = w + (k8 * 8) * N_DIM + n0 + kcol;

  // prologue: W regs for iter 0 (8 dword loads; 32 lanes x 4B = 128B/row segment)
  int L[8];
#pragma unroll
  for (int i = 0; i < 8; ++i) L[i] = wbase[i * N_DIM];

  f32x16 acc = {};

  // A-fragment base: wave's m-tile, chunk units of 16 B
  const bf16x8* afrag = (const bf16x8*)xb + (size_t)(wave * KSTEPS) * 64;

#pragma unroll 1
  for (int it = 0; it < NIT; ++it) {
    // int32 -> bf16 pack (exact: |w|<=128): pairs of consecutive k per dword
    i32x4 ch;
#pragma unroll
    for (int d = 0; d < 4; ++d) {
      float a0 = (float)L[2 * d];
      float a1 = (float)L[2 * d + 1];
      ch[d] = (int)__builtin_amdgcn_perm(fbits(a1), fbits(a0), 0x07060302u);
    }
    Blds[it & 1][slot] = ch;
    __syncthreads();   // ONLY barrier this iter: buf[it&1] ready; buf[(it+1)&1]
                       // writes at it+1 are safe (each wave's ds_reads drained
                       // by its own pre-barrier lgkmcnt before it arrives here)

    // W prefetch for it+1 — issued right after barrier, consumed at next iter's
    // top: ~full compute phase (>900cyc HBM latency) in flight
    if (it + 1 < NIT) {
      const int* wp = wbase + (it + 1) * BK * N_DIM;
#pragma unroll
      for (int i = 0; i < 8; ++i) L[i] = wp[i * N_DIM];
    }

    // A-frags: coalesced 1 KiB wave reads, L1/L2-hot (younger than W loads, so
    // waiting on them never drains the W HBM queue)
    bf16x8 A[8];
#pragma unroll
    for (int s = 0; s < 8; ++s) A[s] = afrag[(it * 8 + s) * 64 + lane];

#pragma unroll
    for (int s = 0; s < 8; ++s) {
      bf16x8 b = *(const bf16x8*)&Blds[it & 1][s * 64 + lane];
      acc = __builtin_amdgcn_mfma_f32_32x32x16_bf16(A[s], b, acc, 0, 0, 0);
    }
  }

  // epilogue: C/D map col=lane&31, row=(reg&3)+8*(reg>>2)+4*(lane>>5)
  const int n = n0 + l31;
  const float sc = scale[n];
  const float bs = bias[n];
#pragma unroll
  for (int g = 0; g < 16; ++g) {
    const int m = wave * 32 + (g & 3) + 8 * (g >> 2) + 4 * half;
    out[m * N_DIM + n] = acc[g] * sc + bs;
  }
}

extern "C" void kernel_launch(void* const* d_in, const int* in_sizes, int n_in,
                              void* d_out, int out_size, void* d_ws, size_t ws_size,
                              hipStream_t stream) {
  const float* x     = (const float*)d_in[0];   // [8,32,4096] fp32
  const int*   wgt   = (const int*)d_in[1];     // [4096,16384] int32
  const float* scale = (const float*)d_in[2];   // [1,16384]
  const float* bias  = (const float*)d_in[3];   // [16384]
  float* out = (float*)d_out;
  unsigned short* xb = (unsigned short*)d_ws;   // 2 MiB fragment-major bf16 x

  cvt_x_frag<<<512, 256, 0, stream>>>(x, xb);
  gemm_qconv<<<N_DIM / BN, 512, 0, stream>>>(xb, wgt, scale, bias, out);
}